// Round 1
// baseline (988.765 us; speedup 1.0000x reference)
//
#include <hip/hip_runtime.h>

#define NH 8
#define DH 32
#define ROWS 128          // tokens per block (16 batches x 8 tokens)
#define XLD 264           // stage buffer leading dim (k), padded for 16B align + bank stagger
#define SLD 36            // q/k/v slab leading dim (8B-aligned rows, odd-ish bank stagger)

typedef __attribute__((ext_vector_type(8))) short bf16x8;
typedef __attribute__((ext_vector_type(4))) float f32x4;

__device__ __forceinline__ unsigned short f2bf(float f) {
  // round-to-nearest-even bf16 (finite inputs only)
  unsigned u = __float_as_uint(f);
  u = (u + 0x7fffu + ((u >> 16) & 1u)) >> 16;
  return (unsigned short)u;
}
__device__ __forceinline__ float bf2f(unsigned short u) {
  return __uint_as_float(((unsigned)u) << 16);
}

// ---------------- prep: transpose+cast weights, gather bias matrix ----------------
__global__ void prep_kernel(const float* __restrict__ wqkv, const float* __restrict__ wout,
                            const float* __restrict__ table, const int* __restrict__ relidx,
                            unsigned short* __restrict__ wqkvT, unsigned short* __restrict__ woutT,
                            float* __restrict__ biasM) {
  const int b = blockIdx.x, t = threadIdx.x;
  if (b < 768) {
    // wqkvT[n][k] = bf16(wqkv[k][n]),  n = b, k = t
    wqkvT[b * 256 + t] = f2bf(wqkv[t * 768 + b]);
  } else if (b < 1024) {
    const int n = b - 768;
    woutT[n * 256 + t] = f2bf(wout[t * 256 + n]);
  } else {
    for (int e = t; e < 512; e += 256) {
      const int hh = e >> 6, ij = e & 63;
      biasM[e] = table[relidx[ij] * NH + hh];   // biasM[h][i*8+j]
    }
  }
}

// ---------------- fused main kernel ----------------
__global__ __launch_bounds__(256, 1)
void attn_main(const float* __restrict__ x,
               const float* __restrict__ ln_w,
               const float* __restrict__ ln_b,
               const unsigned short* __restrict__ wqkvT,
               const unsigned short* __restrict__ woutT,
               const float* __restrict__ biasM,
               float* __restrict__ out) {
  __shared__ unsigned short s_stage[ROWS * XLD];      // 67584 B: weight staging
  __shared__ unsigned short s_ao[NH * ROWS * DH];     // 65536 B: attention out, head-major
  __shared__ unsigned short s_q[ROWS * SLD];          // 9216 B each
  __shared__ unsigned short s_k[ROWS * SLD];
  __shared__ unsigned short s_v[ROWS * SLD];

  const int tid  = threadIdx.x;
  const int w    = tid >> 6;        // wave 0..3
  const int lane = tid & 63;
  const int l15  = lane & 15;
  const int quad = lane >> 4;
  const int row0 = blockIdx.x * ROWS;

  // ---- LayerNorm directly into register-resident A-fragments ----
  // lane holds A[m=lane&15][k=quad*8+j] for kstep kk; wave w owns m-tiles {2w, 2w+1}
  bf16x8 afrag[2][8];
  #pragma unroll
  for (int mt = 0; mt < 2; ++mt) {
    const int lrow = (2 * w + mt) * 16 + l15;
    const float* xr = x + (size_t)(row0 + lrow) * 256;
    float4 xv[16];
    float sum = 0.f, ss = 0.f;
    #pragma unroll
    for (int kk = 0; kk < 8; ++kk) {
      #pragma unroll
      for (int i = 0; i < 2; ++i) {
        const float4 v = *(const float4*)(xr + kk * 32 + quad * 8 + i * 4);
        xv[kk * 2 + i] = v;
        sum += v.x + v.y + v.z + v.w;
        ss  += v.x * v.x + v.y * v.y + v.z * v.z + v.w * v.w;
      }
    }
    // reduce across the 4 lanes sharing this row (lanes m, m+16, m+32, m+48)
    sum += __shfl_xor(sum, 16); ss += __shfl_xor(ss, 16);
    sum += __shfl_xor(sum, 32); ss += __shfl_xor(ss, 32);
    const float mean = sum * (1.f / 256.f);
    const float var  = ss * (1.f / 256.f) - mean * mean;
    const float rstd = rsqrtf(var + 1e-5f);
    #pragma unroll
    for (int kk = 0; kk < 8; ++kk) {
      union { bf16x8 v; unsigned short e[8]; } pk;
      #pragma unroll
      for (int i = 0; i < 2; ++i) {
        const float4 g   = *(const float4*)(ln_w + kk * 32 + quad * 8 + i * 4);
        const float4 bta = *(const float4*)(ln_b + kk * 32 + quad * 8 + i * 4);
        const float4 v = xv[kk * 2 + i];
        pk.e[i * 4 + 0] = f2bf((v.x - mean) * rstd * g.x + bta.x);
        pk.e[i * 4 + 1] = f2bf((v.y - mean) * rstd * g.y + bta.y);
        pk.e[i * 4 + 2] = f2bf((v.z - mean) * rstd * g.z + bta.z);
        pk.e[i * 4 + 3] = f2bf((v.w - mean) * rstd * g.w + bta.w);
      }
      afrag[mt][kk] = pk.v;
    }
  }

  // ---- per-head: stage W -> QKV MFMA -> slabs -> attention -> s_ao ----
  for (int h = 0; h < NH; ++h) {
    // stage head slab of W_qkv^T: 96 rows (q16|q16|k16|k16|v16|v16) x 256 k
    for (int c = tid; c < 96 * 32; c += 256) {
      const int r = c >> 5;
      const int o = (c & 31) * 8;
      const int gRow = (r >> 5) * 256 + h * 32 + (r & 31);
      *(uint4*)&s_stage[r * XLD + o] = *(const uint4*)&wqkvT[gRow * 256 + o];
    }
    __syncthreads();

    const f32x4 fz = {0.f, 0.f, 0.f, 0.f};
    f32x4 acc[2][6];
    #pragma unroll
    for (int mt = 0; mt < 2; ++mt)
      #pragma unroll
      for (int t = 0; t < 6; ++t) acc[mt][t] = fz;

    #pragma unroll
    for (int kk = 0; kk < 8; ++kk) {
      const int ko = kk * 32 + quad * 8;
      const bf16x8 a0 = afrag[0][kk];
      const bf16x8 a1 = afrag[1][kk];
      #pragma unroll
      for (int t = 0; t < 6; ++t) {
        const bf16x8 b = *(const bf16x8*)&s_stage[(t * 16 + l15) * XLD + ko];
        acc[0][t] = __builtin_amdgcn_mfma_f32_16x16x32_bf16(a0, b, acc[0][t], 0, 0, 0);
        acc[1][t] = __builtin_amdgcn_mfma_f32_16x16x32_bf16(a1, b, acc[1][t], 0, 0, 0);
      }
    }

    // C layout: col = lane&15, row = quad*4 + r   -> scatter to q/k/v slabs (bf16)
    #pragma unroll
    for (int mt = 0; mt < 2; ++mt) {
      #pragma unroll
      for (int t = 0; t < 6; ++t) {
        const int s = t >> 1, u = t & 1;
        unsigned short* slab = (s == 0) ? s_q : (s == 1) ? s_k : s_v;
        const float mul = (s == 0) ? 0.17677669529663687f : 1.f;  // 32^-0.5 folded into q
        #pragma unroll
        for (int r = 0; r < 4; ++r) {
          const int row = (2 * w + mt) * 16 + quad * 4 + r;
          slab[row * SLD + u * 16 + l15] = f2bf(acc[mt][t][r] * mul);
        }
      }
    }
    __syncthreads();

    // ---- attention (scalar fp32), 2 threads per token row ----
    {
      const int i = tid >> 1;       // token row 0..127
      const int half = tid & 1;
      const int bl = i >> 3;        // local batch
      const int ti = i & 7;         // query pos within window+reg
      float qv[32];
      #pragma unroll
      for (int c = 0; c < 8; ++c) {
        const ushort4 uq = *(const ushort4*)&s_q[i * SLD + c * 4];
        qv[c * 4 + 0] = bf2f(uq.x); qv[c * 4 + 1] = bf2f(uq.y);
        qv[c * 4 + 2] = bf2f(uq.z); qv[c * 4 + 3] = bf2f(uq.w);
      }
      float sm[4];
      #pragma unroll
      for (int jj = 0; jj < 4; ++jj) {
        const int j = half * 4 + jj;
        const int kr = bl * 8 + j;
        float d = 0.f;
        #pragma unroll
        for (int c = 0; c < 8; ++c) {
          const ushort4 uk = *(const ushort4*)&s_k[kr * SLD + c * 4];
          d += qv[c * 4 + 0] * bf2f(uk.x) + qv[c * 4 + 1] * bf2f(uk.y)
             + qv[c * 4 + 2] * bf2f(uk.z) + qv[c * 4 + 3] * bf2f(uk.w);
        }
        sm[jj] = d + biasM[h * 64 + ti * 8 + j];
      }
      float s8[8];
      #pragma unroll
      for (int jj = 0; jj < 4; ++jj) {
        const float o = __shfl_xor(sm[jj], 1);
        s8[half * 4 + jj] = sm[jj];
        s8[(1 - half) * 4 + jj] = o;
      }
      float mx = s8[0];
      #pragma unroll
      for (int j = 1; j < 8; ++j) mx = fmaxf(mx, s8[j]);
      float ex[8], sumw = 0.f;
      #pragma unroll
      for (int j = 0; j < 8; ++j) { ex[j] = __expf(s8[j] - mx); sumw += ex[j]; }
      const float inv = 1.f / sumw;
      float o16[16];
      #pragma unroll
      for (int d = 0; d < 16; ++d) o16[d] = 0.f;
      #pragma unroll
      for (int j = 0; j < 8; ++j) {
        const float p = ex[j] * inv;
        const int vr = bl * 8 + j;
        #pragma unroll
        for (int c = 0; c < 4; ++c) {
          const ushort4 uv = *(const ushort4*)&s_v[vr * SLD + half * 16 + c * 4];
          o16[c * 4 + 0] += p * bf2f(uv.x); o16[c * 4 + 1] += p * bf2f(uv.y);
          o16[c * 4 + 2] += p * bf2f(uv.z); o16[c * 4 + 3] += p * bf2f(uv.w);
        }
      }
      unsigned short* dst = &s_ao[(h * ROWS + i) * DH + half * 16];
      #pragma unroll
      for (int c = 0; c < 4; ++c) {
        ushort4 pw;
        pw.x = f2bf(o16[c * 4 + 0]); pw.y = f2bf(o16[c * 4 + 1]);
        pw.z = f2bf(o16[c * 4 + 2]); pw.w = f2bf(o16[c * 4 + 3]);
        *(ushort4*)&dst[c * 4] = pw;
      }
    }
    __syncthreads();
  }

  // ---- output projection: out = ao @ w_out (kstep kk == head kk) ----
  for (int p = 0; p < 2; ++p) {
    for (int c = tid; c < 128 * 32; c += 256) {
      const int r = c >> 5;
      const int o = (c & 31) * 8;
      *(uint4*)&s_stage[r * XLD + o] = *(const uint4*)&woutT[(p * 128 + r) * 256 + o];
    }
    __syncthreads();

    const f32x4 fz = {0.f, 0.f, 0.f, 0.f};
    f32x4 oacc[2][8];
    #pragma unroll
    for (int mt = 0; mt < 2; ++mt)
      #pragma unroll
      for (int nt = 0; nt < 8; ++nt) oacc[mt][nt] = fz;

    #pragma unroll
    for (int kk = 0; kk < 8; ++kk) {
      const bf16x8 a0 = *(const bf16x8*)&s_ao[(kk * ROWS + (2 * w) * 16 + l15) * DH + quad * 8];
      const bf16x8 a1 = *(const bf16x8*)&s_ao[(kk * ROWS + (2 * w + 1) * 16 + l15) * DH + quad * 8];
      #pragma unroll
      for (int nt = 0; nt < 8; ++nt) {
        const bf16x8 b = *(const bf16x8*)&s_stage[(nt * 16 + l15) * XLD + kk * 32 + quad * 8];
        oacc[0][nt] = __builtin_amdgcn_mfma_f32_16x16x32_bf16(a0, b, oacc[0][nt], 0, 0, 0);
        oacc[1][nt] = __builtin_amdgcn_mfma_f32_16x16x32_bf16(a1, b, oacc[1][nt], 0, 0, 0);
      }
    }
    #pragma unroll
    for (int mt = 0; mt < 2; ++mt)
      #pragma unroll
      for (int nt = 0; nt < 8; ++nt)
        #pragma unroll
        for (int r = 0; r < 4; ++r) {
          const int grow = row0 + (2 * w + mt) * 16 + quad * 4 + r;
          out[(size_t)grow * 256 + p * 128 + nt * 16 + l15] = oacc[mt][nt][r];
        }
    __syncthreads();
  }
}

extern "C" void kernel_launch(void* const* d_in, const int* in_sizes, int n_in,
                              void* d_out, int out_size, void* d_ws, size_t ws_size,
                              hipStream_t stream) {
  const float* x      = (const float*)d_in[0];
  const float* ln_w   = (const float*)d_in[1];
  const float* ln_b   = (const float*)d_in[2];
  const float* wqkv   = (const float*)d_in[3];
  const float* wout   = (const float*)d_in[4];
  const float* table  = (const float*)d_in[5];
  const int*   relidx = (const int*)d_in[6];
  float* out = (float*)d_out;

  unsigned short* wqkvT = (unsigned short*)d_ws;        // 768*256 bf16
  unsigned short* woutT = wqkvT + 768 * 256;            // 256*256 bf16
  float* biasM = (float*)(woutT + 256 * 256);           // 8*64 fp32

  prep_kernel<<<1025, 256, 0, stream>>>(wqkv, wout, table, relidx, wqkvT, woutT, biasM);
  attn_main<<<2048, 256, 0, stream>>>(x, ln_w, ln_b, wqkvT, woutT, biasM, out);
}